// Round 1
// baseline (33.938 us; speedup 1.0000x reference)
//
#include <hip/hip_runtime.h>
#include <math.h>

// Problem constants (reference: B=8, N=4096, M=4096, D=2)
#define NB 8
#define NPTS 4096
#define MPTS 4096
#define BN (NB * NPTS)
#define CHUNK 64                 // predicted points per block = 1 wave
#define NCHUNK (NPTS / CHUNK)    // 64 chunks per batch

__device__ __forceinline__ float waveReduceSum(float v) {
#pragma unroll
    for (int off = 32; off > 0; off >>= 1)
        v += __shfl_down(v, off, 64);
    return v;
}

// One wave computes min squared distance for 64 predicted points against a
// (possibly split) range of targets staged in LDS.
// WRITE_MIN: write per-pred min to out_min[ts*BN + b*N + n]  (split path)
// else:      mask invalid preds, wave-reduce sum, write out_partials[g]
template <int TSPLIT, bool WRITE_MIN>
__global__ __launch_bounds__(CHUNK) void nn_kernel(
    const float2* __restrict__ pred,    // [B][N]
    const int* __restrict__ pcounts,    // [B]
    const float2* __restrict__ tgt,     // [B][M]
    const int* __restrict__ tcounts,    // [B]
    float* __restrict__ out_min,        // [TSPLIT][B*N]   (WRITE_MIN)
    float* __restrict__ out_partials)   // [B*NCHUNK]      (!WRITE_MIN)
{
    constexpr int THALF = MPTS / TSPLIT;
    __shared__ float2 tl[THALF];

    int bid = blockIdx.x;
    int ts, g;
    if (TSPLIT > 1) { ts = bid % TSPLIT; g = bid / TSPLIT; }
    else            { ts = 0;            g = bid; }
    const int b = g / NCHUNK;
    const int c = g % NCHUNK;
    const int lane = threadIdx.x;

    const int tcount = tcounts[b];
    const int tstart = ts * THALF;
    int tloc = min(tcount - tstart, THALF);
    if (tloc < 0) tloc = 0;

    // Stage targets into LDS as float4 (2 points per load), fully coalesced.
    const float4* src = (const float4*)(tgt + (size_t)b * MPTS + tstart);
    float4* dst = (float4*)tl;
#pragma unroll
    for (int i = 0; i < THALF / 2 / CHUNK; ++i)
        dst[i * CHUNK + lane] = src[i * CHUNK + lane];
    __syncthreads();

    const float2 p = pred[(size_t)b * NPTS + c * CHUNK + lane];

    float m0 = INFINITY, m1 = INFINITY, m2 = INFINITY, m3 = INFINITY;
    const int t4 = tloc & ~3;
    int m = 0;
    for (; m < t4; m += 4) {
        float2 t0 = tl[m + 0], t1 = tl[m + 1], t2 = tl[m + 2], t3 = tl[m + 3];
        float dx0 = p.x - t0.x, dy0 = p.y - t0.y;
        float dx1 = p.x - t1.x, dy1 = p.y - t1.y;
        float dx2 = p.x - t2.x, dy2 = p.y - t2.y;
        float dx3 = p.x - t3.x, dy3 = p.y - t3.y;
        m0 = fminf(m0, fmaf(dx0, dx0, dy0 * dy0));
        m1 = fminf(m1, fmaf(dx1, dx1, dy1 * dy1));
        m2 = fminf(m2, fmaf(dx2, dx2, dy2 * dy2));
        m3 = fminf(m3, fmaf(dx3, dx3, dy3 * dy3));
    }
    for (; m < tloc; ++m) {
        float2 t = tl[m];
        float dx = p.x - t.x, dy = p.y - t.y;
        m0 = fminf(m0, fmaf(dx, dx, dy * dy));
    }
    float mn = fminf(fminf(m0, m1), fminf(m2, m3));

    if (WRITE_MIN) {
        out_min[(size_t)ts * BN + (size_t)b * NPTS + c * CHUNK + lane] = mn;
    } else {
        const int pcount = pcounts[b];
        float v = (c * CHUNK + lane < pcount) ? mn : 0.0f;
        v = waveReduceSum(v);
        if (lane == 0) out_partials[g] = v;
    }
}

// Combine the 2 target-half mins per pred point, mask invalid preds,
// wave-reduce to per-64-point partial sums. grid = BN/256, block = 256.
__global__ __launch_bounds__(256) void combine_kernel(
    const float* __restrict__ mins,     // [2][B*N]
    const int* __restrict__ pcounts,
    float* __restrict__ partials)       // [B*NCHUNK]
{
    const int idx = blockIdx.x * 256 + threadIdx.x;   // 0 .. BN-1
    const int b = idx >> 12;                          // /NPTS
    const int n = idx & (NPTS - 1);
    float v = fminf(mins[idx], mins[BN + idx]);
    v = (n < pcounts[b]) ? v : 0.0f;
    v = waveReduceSum(v);
    if ((threadIdx.x & 63) == 0) partials[idx >> 6] = v;
}

// Final: deterministic fixed-tree reduction of 512 partials -> 3 scalars.
// block = 512 (8 waves, one per batch).
__global__ __launch_bounds__(512) void final_kernel(
    const float* __restrict__ partials, // [B][NCHUNK]
    const int* __restrict__ pcounts,
    const int* __restrict__ tcounts,
    float* __restrict__ out)            // [3]: total, coord, points
{
    __shared__ float bs[NB];
    const int w = threadIdx.x >> 6;     // batch
    const int lane = threadIdx.x & 63;
    float v = partials[w * NCHUNK + lane];
    v = waveReduceSum(v);
    if (lane == 0) bs[w] = v;
    __syncthreads();
    if (threadIdx.x == 0) {
        float coord = 0.0f, pts = 0.0f;
        for (int b = 0; b < NB; ++b) {
            coord += bs[b] / ((float)pcounts[b] * 2.0f);
            float d = ((float)pcounts[b] - (float)tcounts[b]) / (float)NPTS;
            pts += d * d;
        }
        coord *= (1.0f / NB);
        pts *= (1.0f / NB);
        out[0] = coord + 0.1f * pts;
        out[1] = coord;
        out[2] = pts;
    }
}

extern "C" void kernel_launch(void* const* d_in, const int* in_sizes, int n_in,
                              void* d_out, int out_size, void* d_ws, size_t ws_size,
                              hipStream_t stream) {
    const float2* pred    = (const float2*)d_in[0];
    const int*    pcounts = (const int*)d_in[1];
    const float2* tgt     = (const float2*)d_in[2];
    const int*    tcounts = (const int*)d_in[3];
    float* out = (float*)d_out;

    float* partials = (float*)d_ws;            // 512 floats
    float* mins     = partials + NB * NCHUNK;  // 2*BN floats (split path)

    const size_t need = (size_t)(NB * NCHUNK + 2 * BN) * sizeof(float);
    if (ws_size >= need) {
        // Target dim split in 2: 1024 blocks -> ~1 wave per SIMD chip-wide.
        nn_kernel<2, true><<<NB * NCHUNK * 2, CHUNK, 0, stream>>>(
            pred, pcounts, tgt, tcounts, mins, nullptr);
        combine_kernel<<<BN / 256, 256, 0, stream>>>(mins, pcounts, partials);
    } else {
        nn_kernel<1, false><<<NB * NCHUNK, CHUNK, 0, stream>>>(
            pred, pcounts, tgt, tcounts, nullptr, partials);
    }
    final_kernel<<<1, 512, 0, stream>>>(partials, pcounts, tcounts, out);
}

// Round 2
// 20.329 us; speedup vs baseline: 1.6694x; 1.6694x over previous
//
#include <hip/hip_runtime.h>
#include <math.h>

// Problem constants (reference: B=8, N=4096, M=4096, D=2)
#define NB 8
#define NPTS 4096
#define MPTS 4096
#define CHUNK 64                  // predicted points per block
#define NCHUNK (NPTS / CHUNK)     // 64 chunks per batch
#define NWAVE 8                   // waves per block (512 threads)
#define TQ (MPTS / NWAVE)         // 512 targets per wave slice

__device__ __forceinline__ float waveReduceSum(float v) {
#pragma unroll
    for (int off = 32; off > 0; off >>= 1)
        v += __shfl_down(v, off, 64);
    return v;
}

// One block = 64 predicted points of batch b; 8 waves split the target range.
// min ||p-t||^2 = p.p + min_t (t.t - 2 p.t)  -- 3 VALU ops per pair with
// (-2tx, -2ty, t.t) precomputed into LDS (SoA; uniform-address b128 broadcast
// reads in the hot loop, conflict-free).
__global__ __launch_bounds__(NWAVE * 64) void nn_kernel(
    const float2* __restrict__ pred,    // [B][N]
    const int* __restrict__ pcounts,    // [B]
    const float2* __restrict__ tgt,     // [B][M]
    const int* __restrict__ tcounts,    // [B]
    float* __restrict__ partials)       // [B*NCHUNK]
{
    __shared__ float sx[MPTS];          // -2*tx
    __shared__ float sy[MPTS];          // -2*ty
    __shared__ float sc[MPTS];          // tx^2+ty^2
    __shared__ float mnw[NWAVE][CHUNK];

    const int g = blockIdx.x;
    const int b = g >> 6;               // / NCHUNK
    const int c = g & (NCHUNK - 1);
    const int w = threadIdx.x >> 6;     // wave id
    const int lane = threadIdx.x & 63;

    const int tcount = tcounts[b];
    const int tstart = w * TQ;

    // Stage this wave's own slice (read back only by this wave -> no barrier).
    const float2* tsrc = tgt + (size_t)b * MPTS + tstart;
#pragma unroll
    for (int i = 0; i < TQ / 64; ++i) {
        float2 t = tsrc[i * 64 + lane];
        int idx = tstart + i * 64 + lane;
        sx[idx] = -2.0f * t.x;
        sy[idx] = -2.0f * t.y;
        sc[idx] = fmaf(t.x, t.x, t.y * t.y);
    }

    const float2 p = pred[(size_t)b * NPTS + c * CHUNK + lane];

    int tloc = min(tcount - tstart, TQ);
    if (tloc < 0) tloc = 0;

    float m0 = INFINITY, m1 = INFINITY, m2 = INFINITY, m3 = INFINITY;
    const float4* x4 = (const float4*)&sx[tstart];
    const float4* y4 = (const float4*)&sy[tstart];
    const float4* c4 = (const float4*)&sc[tstart];
    const int nt4 = tloc >> 2;
    for (int i = 0; i < nt4; ++i) {
        float4 xv = x4[i], yv = y4[i], cv = c4[i];
        m0 = fminf(m0, fmaf(p.y, yv.x, fmaf(p.x, xv.x, cv.x)));
        m1 = fminf(m1, fmaf(p.y, yv.y, fmaf(p.x, xv.y, cv.y)));
        m2 = fminf(m2, fmaf(p.y, yv.z, fmaf(p.x, xv.z, cv.z)));
        m3 = fminf(m3, fmaf(p.y, yv.w, fmaf(p.x, xv.w, cv.w)));
    }
    for (int m = nt4 * 4; m < tloc; ++m) {
        float v = fmaf(p.y, sy[tstart + m], fmaf(p.x, sx[tstart + m], sc[tstart + m]));
        m0 = fminf(m0, v);
    }
    mnw[w][lane] = fminf(fminf(m0, m1), fminf(m2, m3));
    __syncthreads();

    if (w == 0) {
        float mn = mnw[0][lane];
#pragma unroll
        for (int j = 1; j < NWAVE; ++j) mn = fminf(mn, mnw[j][lane]);
        float pp = fmaf(p.x, p.x, p.y * p.y);
        float v = (c * CHUNK + lane < pcounts[b]) ? (mn + pp) : 0.0f;
        v = waveReduceSum(v);
        if (lane == 0) partials[g] = v;
    }
}

// Final: deterministic fixed-tree reduction of 512 partials -> 3 scalars.
// block = 512 (8 waves, one per batch).
__global__ __launch_bounds__(512) void final_kernel(
    const float* __restrict__ partials, // [B][NCHUNK]
    const int* __restrict__ pcounts,
    const int* __restrict__ tcounts,
    float* __restrict__ out)            // [3]: total, coord, points
{
    __shared__ float bs[NB];
    const int w = threadIdx.x >> 6;     // batch
    const int lane = threadIdx.x & 63;
    float v = partials[w * NCHUNK + lane];
    v = waveReduceSum(v);
    if (lane == 0) bs[w] = v;
    __syncthreads();
    if (threadIdx.x == 0) {
        float coord = 0.0f, pts = 0.0f;
        for (int b = 0; b < NB; ++b) {
            coord += bs[b] / ((float)pcounts[b] * 2.0f);
            float d = ((float)pcounts[b] - (float)tcounts[b]) / (float)NPTS;
            pts += d * d;
        }
        coord *= (1.0f / NB);
        pts *= (1.0f / NB);
        out[0] = coord + 0.1f * pts;
        out[1] = coord;
        out[2] = pts;
    }
}

extern "C" void kernel_launch(void* const* d_in, const int* in_sizes, int n_in,
                              void* d_out, int out_size, void* d_ws, size_t ws_size,
                              hipStream_t stream) {
    const float2* pred    = (const float2*)d_in[0];
    const int*    pcounts = (const int*)d_in[1];
    const float2* tgt     = (const float2*)d_in[2];
    const int*    tcounts = (const int*)d_in[3];
    float* out = (float*)d_out;

    float* partials = (float*)d_ws;     // 512 floats

    nn_kernel<<<NB * NCHUNK, NWAVE * 64, 0, stream>>>(
        pred, pcounts, tgt, tcounts, partials);
    final_kernel<<<1, 512, 0, stream>>>(partials, pcounts, tcounts, out);
}

// Round 3
// 19.693 us; speedup vs baseline: 1.7233x; 1.0323x over previous
//
#include <hip/hip_runtime.h>
#include <math.h>

// Problem constants (reference: B=8, N=4096, M=4096, D=2)
#define NB 8
#define NPTS 4096
#define MPTS 4096
#define BN (NB * NPTS)            // 32768 predicted points total
#define P 4                       // predicted points per lane (register blocking)
#define WV 4                      // waves per block (256 threads)
#define TT 128                    // targets staged per block (slice size)
#define NS (MPTS / TT)            // 32 target slices
#define PREDS_PER_WAVE (64 * P)   // 256
#define PREDS_PER_BLOCK (PREDS_PER_WAVE * WV)  // 1024
#define PGROUPS (BN / PREDS_PER_BLOCK)         // 32
#define NCHUNK 64                 // partials per batch (4096/64)

__device__ __forceinline__ float waveReduceSum(float v) {
#pragma unroll
    for (int off = 32; off > 0; off >>= 1)
        v += __shfl_down(v, off, 64);
    return v;
}

// One block = 1024 predicted points (4 waves x 256) x one 128-target slice.
// min ||p-t||^2 = p.p + min_t (t.t - 2 p.t): per pair 2 fma + 1 min, with
// (-2tx, -2ty, t.t) staged SoA in LDS. All waves read the same uniform
// addresses (16B broadcast, conflict-free); P=4 preds/lane amortizes each
// LDS issue over 16 pairs so the VALU, not the LDS pipe, is the limiter.
__global__ __launch_bounds__(WV * 64) void nn_kernel(
    const float2* __restrict__ pred,    // [B*N]
    const float2* __restrict__ tgt,     // [B][M]
    const int* __restrict__ tcounts,    // [B]
    float* __restrict__ mins)           // [NS][B*N] partial mins (no p.p term)
{
    __shared__ float sx[TT];            // -2*tx
    __shared__ float sy[TT];            // -2*ty
    __shared__ float sc[TT];            // t.t
    const int bid = blockIdx.x;
    const int s  = bid & (NS - 1);
    const int pg = bid >> 5;            // / NS
    const int b  = pg >> 2;             // PGROUPS/NB = 4 groups per batch
    const int tid = threadIdx.x;

    const int tcount = tcounts[b];
    const int tstart = s * TT;
    const int tloc = min(tcount - tstart, TT);   // may be <= 0 (dead slice)

    if (tid < TT) {
        float2 t = tgt[(size_t)b * MPTS + tstart + tid];
        sx[tid] = -2.0f * t.x;
        sy[tid] = -2.0f * t.y;
        sc[tid] = fmaf(t.x, t.x, t.y * t.y);
    }
    __syncthreads();

    const int w = tid >> 6, lane = tid & 63;
    const size_t pbase = (size_t)pg * PREDS_PER_BLOCK + w * PREDS_PER_WAVE + lane;
    const float2 p0 = pred[pbase];
    const float2 p1 = pred[pbase + 64];
    const float2 p2 = pred[pbase + 128];
    const float2 p3 = pred[pbase + 192];

    float mn0 = INFINITY, mn1 = INFINITY, mn2 = INFINITY, mn3 = INFINITY;

    if (tloc > 0) {
        const float4* x4 = (const float4*)sx;
        const float4* y4 = (const float4*)sy;
        const float4* c4 = (const float4*)sc;
        const int nt4 = tloc >> 2;
#pragma unroll 2
        for (int i = 0; i < nt4; ++i) {
            float4 xv = x4[i], yv = y4[i], cv = c4[i];
            mn0 = fminf(mn0, fmaf(p0.y, yv.x, fmaf(p0.x, xv.x, cv.x)));
            mn1 = fminf(mn1, fmaf(p1.y, yv.x, fmaf(p1.x, xv.x, cv.x)));
            mn2 = fminf(mn2, fmaf(p2.y, yv.x, fmaf(p2.x, xv.x, cv.x)));
            mn3 = fminf(mn3, fmaf(p3.y, yv.x, fmaf(p3.x, xv.x, cv.x)));
            mn0 = fminf(mn0, fmaf(p0.y, yv.y, fmaf(p0.x, xv.y, cv.y)));
            mn1 = fminf(mn1, fmaf(p1.y, yv.y, fmaf(p1.x, xv.y, cv.y)));
            mn2 = fminf(mn2, fmaf(p2.y, yv.y, fmaf(p2.x, xv.y, cv.y)));
            mn3 = fminf(mn3, fmaf(p3.y, yv.y, fmaf(p3.x, xv.y, cv.y)));
            mn0 = fminf(mn0, fmaf(p0.y, yv.z, fmaf(p0.x, xv.z, cv.z)));
            mn1 = fminf(mn1, fmaf(p1.y, yv.z, fmaf(p1.x, xv.z, cv.z)));
            mn2 = fminf(mn2, fmaf(p2.y, yv.z, fmaf(p2.x, xv.z, cv.z)));
            mn3 = fminf(mn3, fmaf(p3.y, yv.z, fmaf(p3.x, xv.z, cv.z)));
            mn0 = fminf(mn0, fmaf(p0.y, yv.w, fmaf(p0.x, xv.w, cv.w)));
            mn1 = fminf(mn1, fmaf(p1.y, yv.w, fmaf(p1.x, xv.w, cv.w)));
            mn2 = fminf(mn2, fmaf(p2.y, yv.w, fmaf(p2.x, xv.w, cv.w)));
            mn3 = fminf(mn3, fmaf(p3.y, yv.w, fmaf(p3.x, xv.w, cv.w)));
        }
        for (int m = nt4 * 4; m < tloc; ++m) {
            float xs = sx[m], ys = sy[m], cs = sc[m];
            mn0 = fminf(mn0, fmaf(p0.y, ys, fmaf(p0.x, xs, cs)));
            mn1 = fminf(mn1, fmaf(p1.y, ys, fmaf(p1.x, xs, cs)));
            mn2 = fminf(mn2, fmaf(p2.y, ys, fmaf(p2.x, xs, cs)));
            mn3 = fminf(mn3, fmaf(p3.y, ys, fmaf(p3.x, xs, cs)));
        }
    }
    float* dst = mins + (size_t)s * BN + pbase;
    dst[0]   = mn0;
    dst[64]  = mn1;
    dst[128] = mn2;
    dst[192] = mn3;
}

// Min over the 32 slices, add p.p, mask invalid preds, wave-reduce to
// per-64-point partial sums. grid = BN/256, block = 256.
__global__ __launch_bounds__(256) void combine_kernel(
    const float* __restrict__ mins,     // [NS][B*N]
    const float2* __restrict__ pred,
    const int* __restrict__ pcounts,
    float* __restrict__ partials)       // [B*NCHUNK]
{
    const int idx = blockIdx.x * 256 + threadIdx.x;   // 0 .. BN-1
    const int b = idx >> 12;
    const int n = idx & (NPTS - 1);
    float v = mins[idx];
#pragma unroll
    for (int s = 1; s < NS; ++s) v = fminf(v, mins[(size_t)s * BN + idx]);
    float2 p = pred[idx];
    v += fmaf(p.x, p.x, p.y * p.y);
    v = (n < pcounts[b]) ? v : 0.0f;
    v = waveReduceSum(v);
    if ((threadIdx.x & 63) == 0) partials[idx >> 6] = v;
}

// Final: deterministic fixed-tree reduction of 512 partials -> 3 scalars.
// block = 512 (8 waves, one per batch).
__global__ __launch_bounds__(512) void final_kernel(
    const float* __restrict__ partials, // [B][NCHUNK]
    const int* __restrict__ pcounts,
    const int* __restrict__ tcounts,
    float* __restrict__ out)            // [3]: total, coord, points
{
    __shared__ float bs[NB];
    const int w = threadIdx.x >> 6;     // batch
    const int lane = threadIdx.x & 63;
    float v = partials[w * NCHUNK + lane];
    v = waveReduceSum(v);
    if (lane == 0) bs[w] = v;
    __syncthreads();
    if (threadIdx.x == 0) {
        float coord = 0.0f, pts = 0.0f;
        for (int b = 0; b < NB; ++b) {
            coord += bs[b] / ((float)pcounts[b] * 2.0f);
            float d = ((float)pcounts[b] - (float)tcounts[b]) / (float)NPTS;
            pts += d * d;
        }
        coord *= (1.0f / NB);
        pts *= (1.0f / NB);
        out[0] = coord + 0.1f * pts;
        out[1] = coord;
        out[2] = pts;
    }
}

extern "C" void kernel_launch(void* const* d_in, const int* in_sizes, int n_in,
                              void* d_out, int out_size, void* d_ws, size_t ws_size,
                              hipStream_t stream) {
    const float2* pred    = (const float2*)d_in[0];
    const int*    pcounts = (const int*)d_in[1];
    const float2* tgt     = (const float2*)d_in[2];
    const int*    tcounts = (const int*)d_in[3];
    float* out = (float*)d_out;

    float* partials = (float*)d_ws;               // 512 floats
    float* mins     = partials + NB * NCHUNK;     // NS*BN floats (4 MB)

    nn_kernel<<<PGROUPS * NS, WV * 64, 0, stream>>>(pred, tgt, tcounts, mins);
    combine_kernel<<<BN / 256, 256, 0, stream>>>(mins, pred, pcounts, partials);
    final_kernel<<<1, 512, 0, stream>>>(partials, pcounts, tcounts, out);
}